// Round 6
// baseline (98.255 us; speedup 1.0000x reference)
//
#include <hip/hip_runtime.h>
#include <hip/hip_bf16.h>

// SoftModule fused forward, MI355X gfx950 — v6.
// S1/T: direct per-lane register loads with depth-3 rotating software
// pipeline (no LDS ring, no DMA, no inline asm). Lane l loads exactly its
// MFMA A-fragment: row (l&15), dwords (l>>4)*4. Compiler's per-register
// vmcnt tracking gives counted waits with 3-iteration slack for A and B.
// Mid phases identical to v5 (verified). LDS 20480 B (p overlays x/a).

using f32x4 = __attribute__((ext_vector_type(4))) float;
using h16x4 = __attribute__((ext_vector_type(4))) _Float16;
using u32x4 = __attribute__((ext_vector_type(4))) unsigned int;
using u32x2 = __attribute__((ext_vector_type(2))) unsigned int;

#define MFMA16(a, b, c) __builtin_amdgcn_mfma_f32_16x16x16f16((a), (b), (c), 0, 0, 0)

__device__ __forceinline__ short h_bits(float f) {  // f32 -> f16 bits
  _Float16 h = (_Float16)f;
  return __builtin_bit_cast(short, h);
}

// ---------------- weight convert + transpose/pack to f16 --------------------
// wsh (f16) element offsets:
//   Bp1 [c32][q4][p16][nt4][kk4] @0      (packed Ws1; 32768)
//   Ws2T [64][64] @32768                 WtP [c8][q][p][nt][kk] @36864 (8192)
//   Wa0T [16][64] @45056   Wa1T [16][64] @46080   Wc0T [64][16] @47104
//   We0T [4][32][64] @48128  We1T [4][32][32] @56320  We2T [4][32][32] @60416
// biases f32 (672 floats) in biasf.
__global__ void sm_convert_v6(
    const float* __restrict__ Ws1, const float* __restrict__ Ws2, const float* __restrict__ Wt,
    const float* __restrict__ Wa0, const float* __restrict__ Wa1, const float* __restrict__ Wc0,
    const float* __restrict__ We0, const float* __restrict__ We1, const float* __restrict__ We2,
    const float* __restrict__ bs1, const float* __restrict__ bs2, const float* __restrict__ bt,
    const float* __restrict__ ba0, const float* __restrict__ ba1, const float* __restrict__ bc0,
    const float* __restrict__ be0, const float* __restrict__ be1, const float* __restrict__ be2,
    short* __restrict__ wsh, float* __restrict__ biasf) {
  int d = blockIdx.x * 256 + threadIdx.x;
  if (d < 64512) {
    float v;
    if (d < 32768) {             // Bp1
      int kk = d & 3, nt = (d >> 2) & 3, p = (d >> 4) & 15, q = (d >> 8) & 3, c = d >> 10;
      int k = c * 16 + q * 4 + kk, o = nt * 16 + p;
      v = Ws1[k * 64 + o];
    }
    else if (d < 36864) { int r = d - 32768, o = r >> 6, k = r & 63;   v = Ws2[k * 64 + o]; }
    else if (d < 45056) {        // WtP
      int r = d - 36864;
      int kk = r & 3, nt = (r >> 2) & 3, p = (r >> 4) & 15, q = (r >> 8) & 3, c = r >> 10;
      int k = c * 16 + q * 4 + kk, o = nt * 16 + p;
      v = Wt[k * 64 + o];
    }
    else if (d < 46080) { int r = d - 45056, o = r >> 6, k = r & 63;   v = Wa0[k * 16 + o]; }
    else if (d < 47104) { int r = d - 46080, o = r >> 6, k = r & 63;   v = Wa1[k * 16 + o]; }
    else if (d < 48128) { int r = d - 47104, o = r >> 4, k = r & 15;   v = Wc0[k * 64 + o]; }
    else if (d < 56320) { int r = d - 48128, n = r >> 11, o = (r >> 6) & 31, i = r & 63; v = We0[n * 2048 + i * 32 + o]; }
    else if (d < 60416) { int r = d - 56320, n = r >> 10, o = (r >> 5) & 31, i = r & 31; v = We1[n * 1024 + i * 32 + o]; }
    else                { int r = d - 60416, n = r >> 10, o = (r >> 5) & 31, i = r & 31; v = We2[n * 1024 + i * 32 + o]; }
    wsh[d] = h_bits(v);
  } else if (d < 65184) {
    int r = d - 64512;
    float v;
    if      (r < 64)  v = bs1[r];
    else if (r < 128) v = bs2[r - 64];
    else if (r < 192) v = bt[r - 128];
    else if (r < 208) v = ba0[r - 192];
    else if (r < 224) v = ba1[r - 208];
    else if (r < 288) v = bc0[r - 224];
    else if (r < 416) v = be0[r - 288];
    else if (r < 544) v = be1[r - 416];
    else              v = be2[r - 544];
    biasf[r] = v;
  }
}

// ---------------- fused forward ---------------------------------------------
__global__ __launch_bounds__(256) void sm_fused_v6(
    const float* __restrict__ obs, const float* __restrict__ task,
    const short* __restrict__ wsh, const float* __restrict__ biasf,
    float* __restrict__ out) {
  const int tid  = threadIdx.x;
  const int wave = tid >> 6;
  const int lane = tid & 63;
  const int q    = lane >> 4;   // k-group (A/B) / row-reg group (C/D)
  const int p    = lane & 15;   // row (A) / col (B, C/D)
  const int lrow = wave * 16;
  const int rowblk = blockIdx.x * 64 + lrow;

  // LDS 20480B. Pre-barrier: x[64, stride 144] @0 | a[64, stride 48] @9216.
  // Post-barrier: p[4][64, stride 80] overlays everything @0.
  __shared__ __align__(16) char lds[20480];
  char* x_lds = lds;
  char* a_lds = lds + 9216;
  char* p_lds = lds;   // valid only after the barrier

  const short* Bp1  = wsh;            // packed Ws1
  const short* Ws2T = wsh + 32768;
  const short* WtP  = wsh + 36864;    // packed Wt
  const short* Wa0T = wsh + 45056;
  const short* Wa1T = wsh + 46080;
  const short* Wc0T = wsh + 47104;
  const short* We0T = wsh + 48128;
  const short* We1T = wsh + 56320;
  const short* We2T = wsh + 60416;
  const float* bs1 = biasf;        const float* bs2 = biasf + 64;
  const float* bt  = biasf + 128;  const float* ba0 = biasf + 192;
  const float* ba1 = biasf + 208;  const float* bc0 = biasf + 224;
  const float* be0 = biasf + 288;  const float* be1 = biasf + 416;
  const float* be2 = biasf + 544;

  const f32x4 z4 = {0.f, 0.f, 0.f, 0.f};

  auto stx  = [&](int row, int col, float v) { *(short*)(x_lds + row * 144 + col * 2) = h_bits(v); };
  auto ldx4 = [&](int row, int k0) -> h16x4 { return *(const h16x4*)(x_lds + row * 144 + k0 * 2); };
  auto ldb  = [&](const short* W, int off) -> h16x4 { return *(const h16x4*)(W + off); };
  auto cvtA = [&](const u32x4& u) -> h16x4 {
    float4 v = __builtin_bit_cast(float4, u);
    h16x4 a;
    a[0] = (_Float16)v.x; a[1] = (_Float16)v.y;
    a[2] = (_Float16)v.z; a[3] = (_Float16)v.w;
    return a;
  };
  auto lo2 = [&](const u32x4& u) -> h16x4 { return __builtin_bit_cast(h16x4, (u32x2){u[0], u[1]}); };
  auto hi2 = [&](const u32x4& u) -> h16x4 { return __builtin_bit_cast(h16x4, (u32x2){u[2], u[3]}); };

  // ---- S1: X1 = relu(obs @ Ws1 + bs1), K=512 (32 chunks of 16 f32) ----
  // Depth-3 rotating register pipeline: slot s=c%3 consumed, then refilled
  // for chunk c+3. Loads issued 3 iters before use -> ~3*T_iter vmem slack.
  f32x4 accX[4] = {z4, z4, z4, z4};
  {
    const float* aptr = obs + (size_t)(rowblk + p) * 512 + q * 4;  // per-lane frag addr
    u32x4 Ab[3], B0[3], B1[3];
#pragma unroll
    for (int i = 0; i < 3; ++i) {
      Ab[i] = *(const u32x4*)(aptr + i * 16);
      const short* bp = Bp1 + ((i * 4 + q) * 16 + p) * 16;
      B0[i] = *(const u32x4*)bp;
      B1[i] = *(const u32x4*)(bp + 8);
    }
#pragma unroll
    for (int c = 0; c < 32; ++c) {
      const int s = c % 3;            // compile-time after unroll
      h16x4 a = cvtA(Ab[s]);
      accX[0] = MFMA16(a, lo2(B0[s]), accX[0]);
      accX[1] = MFMA16(a, hi2(B0[s]), accX[1]);
      accX[2] = MFMA16(a, lo2(B1[s]), accX[2]);
      accX[3] = MFMA16(a, hi2(B1[s]), accX[3]);
      if (c + 3 < 32) {
        Ab[s] = *(const u32x4*)(aptr + (c + 3) * 16);
        const short* bp = Bp1 + (((c + 3) * 4 + q) * 16 + p) * 16;
        B0[s] = *(const u32x4*)bp;
        B1[s] = *(const u32x4*)(bp + 8);
      }
    }
  }
#pragma unroll
  for (int nt = 0; nt < 4; ++nt) {
    float bias = bs1[nt * 16 + p];
#pragma unroll
    for (int r = 0; r < 4; ++r)
      stx(lrow + 4 * q + r, nt * 16 + p, fmaxf(accX[nt][r] + bias, 0.f));
  }

  // ---- S2: s = relu(X1 @ Ws2 + bs2), K=64 ----
  f32x4 accS[4] = {z4, z4, z4, z4};
#pragma unroll
  for (int kb = 0; kb < 4; ++kb) {
    h16x4 a = ldx4(lrow + p, kb * 16 + q * 4);
#pragma unroll
    for (int nt = 0; nt < 4; ++nt)
      accS[nt] = MFMA16(a, ldb(Ws2T, (nt * 16 + p) * 64 + kb * 16 + q * 4), accS[nt]);
  }
  float sf[4][4];
#pragma unroll
  for (int nt = 0; nt < 4; ++nt) {
    float bias = bs2[nt * 16 + p];
#pragma unroll
    for (int r = 0; r < 4; ++r) sf[nt][r] = fmaxf(accS[nt][r] + bias, 0.f);
  }
#pragma unroll
  for (int nt = 0; nt < 4; ++nt)
#pragma unroll
    for (int r = 0; r < 4; ++r) stx(lrow + 4 * q + r, nt * 16 + p, sf[nt][r]);

  // ---- T: t = relu(task @ Wt + bt), K=128 (8 chunks), same pipeline ----
  f32x4 accT[4] = {z4, z4, z4, z4};
  {
    const float* aptr = task + (size_t)(rowblk + p) * 128 + q * 4;
    u32x4 Ab[3], B0[3], B1[3];
#pragma unroll
    for (int i = 0; i < 3; ++i) {
      Ab[i] = *(const u32x4*)(aptr + i * 16);
      const short* bp = WtP + ((i * 4 + q) * 16 + p) * 16;
      B0[i] = *(const u32x4*)bp;
      B1[i] = *(const u32x4*)(bp + 8);
    }
#pragma unroll
    for (int c = 0; c < 8; ++c) {
      const int s = c % 3;
      h16x4 a = cvtA(Ab[s]);
      accT[0] = MFMA16(a, lo2(B0[s]), accT[0]);
      accT[1] = MFMA16(a, hi2(B0[s]), accT[1]);
      accT[2] = MFMA16(a, lo2(B1[s]), accT[2]);
      accT[3] = MFMA16(a, hi2(B1[s]), accT[3]);
      if (c + 3 < 8) {
        Ab[s] = *(const u32x4*)(aptr + (c + 3) * 16);
        const short* bp = WtP + (((c + 3) * 4 + q) * 16 + p) * 16;
        B0[s] = *(const u32x4*)bp;
        B1[s] = *(const u32x4*)(bp + 8);
      }
    }
  }
  float r0f[4][4];
#pragma unroll
  for (int nt = 0; nt < 4; ++nt) {
    float bias = bt[nt * 16 + p];
#pragma unroll
    for (int r = 0; r < 4; ++r)
      r0f[nt][r] = sf[nt][r] * fmaxf(accT[nt][r] + bias, 0.f);
  }

  // ---- We0: m[j] = relu(s @ We0[j] + be0[j]), K=64, 32 cols each ----
  float mfr[4][2][4];
#pragma unroll
  for (int n = 0; n < 4; ++n) {
    f32x4 acc[2] = {z4, z4};
#pragma unroll
    for (int kb = 0; kb < 4; ++kb) {
      h16x4 a = ldx4(lrow + p, kb * 16 + q * 4);
#pragma unroll
      for (int nt = 0; nt < 2; ++nt)
        acc[nt] = MFMA16(a, ldb(We0T, (n * 32 + nt * 16 + p) * 64 + kb * 16 + q * 4), acc[nt]);
    }
#pragma unroll
    for (int nt = 0; nt < 2; ++nt) {
      float bias = be0[n * 32 + nt * 16 + p];
#pragma unroll
      for (int r = 0; r < 4; ++r) mfr[n][nt][r] = fmaxf(acc[nt][r] + bias, 0.f);
    }
  }

  // r0 -> x_lds
#pragma unroll
  for (int nt = 0; nt < 4; ++nt)
#pragma unroll
    for (int r = 0; r < 4; ++r) stx(lrow + 4 * q + r, nt * 16 + p, r0f[nt][r]);

  // ---- A0: softmax over groups of 4 of (r0 @ Wa0 + ba0) ----
  f32x4 accA = z4;
#pragma unroll
  for (int kb = 0; kb < 4; ++kb)
    accA = MFMA16(ldx4(lrow + p, kb * 16 + q * 4), ldb(Wa0T, p * 64 + kb * 16 + q * 4), accA);
  float a0v[4];
  {
    float bias = ba0[p];
#pragma unroll
    for (int r = 0; r < 4; ++r) {
      float v = accA[r] + bias;
      float mx = fmaxf(v, __shfl_xor(v, 1));
      mx = fmaxf(mx, __shfl_xor(mx, 2));
      float e = __expf(v - mx);
      float ssum = e + __shfl_xor(e, 1);
      ssum += __shfl_xor(ssum, 2);
      a0v[r] = e / ssum;
    }
  }
#pragma unroll
  for (int r = 0; r < 4; ++r)
    *(short*)(a_lds + (lrow + 4 * q + r) * 48 + p * 2) = h_bits(a0v[r]);

  // ---- combine: prev1[i][b][d] = sum_j a0[b][i][j] * m[j][b][d] ----
  float pv[4][2][4];
#pragma unroll
  for (int i = 0; i < 4; ++i)
#pragma unroll
    for (int nt = 0; nt < 2; ++nt)
#pragma unroll
      for (int r = 0; r < 4; ++r) pv[i][nt][r] = 0.f;
  const int sbase = lane & 48;
#pragma unroll
  for (int r = 0; r < 4; ++r) {
#pragma unroll
    for (int c = 0; c < 16; ++c) {
      float av = __shfl(a0v[r], sbase | c);
      pv[c >> 2][0][r] += av * mfr[c & 3][0][r];
      pv[c >> 2][1][r] += av * mfr[c & 3][1][r];
    }
  }

  // ---- Wc0: r = relu((a0 @ Wc0 + bc0) * r0), K=16 (one MFMA block) ----
  f32x4 accC[4] = {z4, z4, z4, z4};
  {
    h16x4 a = *(const h16x4*)(a_lds + (lrow + p) * 48 + q * 8);
#pragma unroll
    for (int nt = 0; nt < 4; ++nt)
      accC[nt] = MFMA16(a, ldb(Wc0T, (nt * 16 + p) * 16 + q * 4), accC[nt]);
  }
  float rf[4][4];
#pragma unroll
  for (int nt = 0; nt < 4; ++nt) {
    float bias = bc0[nt * 16 + p];
#pragma unroll
    for (int r = 0; r < 4; ++r)
      rf[nt][r] = fmaxf((accC[nt][r] + bias) * r0f[nt][r], 0.f);
  }
#pragma unroll
  for (int nt = 0; nt < 4; ++nt)
#pragma unroll
    for (int r = 0; r < 4; ++r) stx(lrow + 4 * q + r, nt * 16 + p, rf[nt][r]);

  // ---- A1: softmax(r @ Wa1 + ba1) ----
  f32x4 accA1 = z4;
#pragma unroll
  for (int kb = 0; kb < 4; ++kb)
    accA1 = MFMA16(ldx4(lrow + p, kb * 16 + q * 4), ldb(Wa1T, p * 64 + kb * 16 + q * 4), accA1);
  float a1v[4];
  {
    float bias = ba1[p];
#pragma unroll
    for (int r = 0; r < 4; ++r) {
      float v = accA1[r] + bias;
      float mx = fmaxf(v, __shfl_xor(v, 1));
      mx = fmaxf(mx, __shfl_xor(mx, 2));
      float e = __expf(v - mx);
      float ssum = e + __shfl_xor(e, 1);
      ssum += __shfl_xor(ssum, 2);
      a1v[r] = e / ssum;
    }
  }

  // ---- barrier: x/a dead for ALL waves; p_lds overlays them ----
  __syncthreads();

  // ---- prev1 -> p_lds; E1: m1[n] = relu(prev1[n] @ We1[n] + be1[n]), K=32 ----
#pragma unroll
  for (int i = 0; i < 4; ++i)
#pragma unroll
    for (int nt = 0; nt < 2; ++nt)
#pragma unroll
      for (int r = 0; r < 4; ++r)
        *(short*)(p_lds + (i * 64 + lrow + 4 * q + r) * 80 + (nt * 16 + p) * 2) = h_bits(pv[i][nt][r]);

  float m1f[4][2][4];
#pragma unroll
  for (int n = 0; n < 4; ++n) {
    f32x4 acc[2] = {z4, z4};
#pragma unroll
    for (int kb = 0; kb < 2; ++kb) {
      h16x4 a = *(const h16x4*)(p_lds + (n * 64 + lrow + p) * 80 + kb * 32 + q * 8);
#pragma unroll
      for (int nt = 0; nt < 2; ++nt)
        acc[nt] = MFMA16(a, ldb(We1T, (n * 32 + nt * 16 + p) * 32 + kb * 16 + q * 4), acc[nt]);
    }
#pragma unroll
    for (int nt = 0; nt < 2; ++nt) {
      float bias = be1[n * 32 + nt * 16 + p];
#pragma unroll
      for (int r = 0; r < 4; ++r) m1f[n][nt][r] = fmaxf(acc[nt][r] + bias, 0.f);
    }
  }

  // ---- combine 2: prev2 = einsum(a1, m1) ----
#pragma unroll
  for (int i = 0; i < 4; ++i)
#pragma unroll
    for (int nt = 0; nt < 2; ++nt)
#pragma unroll
      for (int r = 0; r < 4; ++r) pv[i][nt][r] = 0.f;
#pragma unroll
  for (int r = 0; r < 4; ++r) {
#pragma unroll
    for (int c = 0; c < 16; ++c) {
      float av = __shfl(a1v[r], sbase | c);
      pv[c >> 2][0][r] += av * m1f[c & 3][0][r];
      pv[c >> 2][1][r] += av * m1f[c & 3][1][r];
    }
  }

  // ---- prev2 -> p_lds; E2 + relu + sum over n; store f32 ----
#pragma unroll
  for (int i = 0; i < 4; ++i)
#pragma unroll
    for (int nt = 0; nt < 2; ++nt)
#pragma unroll
      for (int r = 0; r < 4; ++r)
        *(short*)(p_lds + (i * 64 + lrow + 4 * q + r) * 80 + (nt * 16 + p) * 2) = h_bits(pv[i][nt][r]);

  float of[2][4] = {{0.f, 0.f, 0.f, 0.f}, {0.f, 0.f, 0.f, 0.f}};
#pragma unroll
  for (int n = 0; n < 4; ++n) {
    f32x4 acc[2] = {z4, z4};
#pragma unroll
    for (int kb = 0; kb < 2; ++kb) {
      h16x4 a = *(const h16x4*)(p_lds + (n * 64 + lrow + p) * 80 + kb * 32 + q * 8);
#pragma unroll
      for (int nt = 0; nt < 2; ++nt)
        acc[nt] = MFMA16(a, ldb(We2T, (n * 32 + nt * 16 + p) * 32 + kb * 16 + q * 4), acc[nt]);
    }
#pragma unroll
    for (int nt = 0; nt < 2; ++nt) {
      float bias = be2[n * 32 + nt * 16 + p];
#pragma unroll
      for (int r = 0; r < 4; ++r) of[nt][r] += fmaxf(acc[nt][r] + bias, 0.f);
    }
  }
#pragma unroll
  for (int nt = 0; nt < 2; ++nt)
#pragma unroll
    for (int r = 0; r < 4; ++r) {
      int grow = rowblk + 4 * q + r;
      out[(size_t)grow * 32 + nt * 16 + p] = of[nt][r];
    }
}

extern "C" void kernel_launch(void* const* d_in, const int* in_sizes, int n_in,
                              void* d_out, int out_size, void* d_ws, size_t ws_size,
                              hipStream_t stream) {
  (void)in_sizes; (void)n_in; (void)out_size; (void)ws_size;
  const float* obs  = (const float*)d_in[0];
  const float* task = (const float*)d_in[1];
  const float* Ws1 = (const float*)d_in[2];  const float* bs1 = (const float*)d_in[3];
  const float* Ws2 = (const float*)d_in[4];  const float* bs2 = (const float*)d_in[5];
  const float* Wt  = (const float*)d_in[6];  const float* bt  = (const float*)d_in[7];
  const float* Wa0 = (const float*)d_in[8];  const float* ba0 = (const float*)d_in[9];
  const float* Wa1 = (const float*)d_in[10]; const float* ba1 = (const float*)d_in[11];
  const float* Wc0 = (const float*)d_in[12]; const float* bc0 = (const float*)d_in[13];
  // d_in[14]=Wc1, d_in[15]=bc1: dead code in the reference (result unused)
  const float* We0 = (const float*)d_in[16]; const float* be0 = (const float*)d_in[17];
  const float* We1 = (const float*)d_in[18]; const float* be1 = (const float*)d_in[19];
  const float* We2 = (const float*)d_in[20]; const float* be2 = (const float*)d_in[21];

  short* wsh   = (short*)d_ws;
  float* biasf = (float*)((char*)d_ws + 129040);

  sm_convert_v6<<<dim3(255), dim3(256), 0, stream>>>(
      Ws1, Ws2, Wt, Wa0, Wa1, Wc0, We0, We1, We2,
      bs1, bs2, bt, ba0, ba1, bc0, be0, be1, be2,
      wsh, biasf);
  sm_fused_v6<<<dim3(1024), dim3(256), 0, stream>>>(
      obs, task, wsh, biasf, (float*)d_out);
}

// Round 7
// 79.668 us; speedup vs baseline: 1.2333x; 1.2333x over previous
//
#include <hip/hip_runtime.h>
#include <hip/hip_bf16.h>

// SoftModule fused forward, MI355X gfx950 — v7.
// S1/T: WG-cooperative global_load_lds staging, 8KB chunks (64 rows x K=32
// f32), double-buffered, 2 barriers/step, provably-safe vmcnt(2) counting
// (2 KB/wave always in flight -> 32 KB/CU >> BW*latency). Global-source
// XOR swizzle (col4 ^= row&7), linear LDS dest, un-XOR on ds_read_b128.
// Mid phases identical to v3..v6 (verified, absmax 0.03125).

using f32x4 = __attribute__((ext_vector_type(4))) float;
using h16x4 = __attribute__((ext_vector_type(4))) _Float16;
using u32x4 = __attribute__((ext_vector_type(4))) unsigned int;
using u32x2 = __attribute__((ext_vector_type(2))) unsigned int;

#define MFMA16(a, b, c) __builtin_amdgcn_mfma_f32_16x16x16f16((a), (b), (c), 0, 0, 0)

__device__ __forceinline__ short h_bits(float f) {  // f32 -> f16 bits
  _Float16 h = (_Float16)f;
  return __builtin_bit_cast(short, h);
}

// async global->LDS, 16B/lane; lds base wave-uniform (HW adds lane*16)
__device__ __forceinline__ void dma16(const float* g, char* l) {
  __builtin_amdgcn_global_load_lds(
      (const __attribute__((address_space(1))) unsigned int*)g,
      (__attribute__((address_space(3))) unsigned int*)l, 16, 0, 0);
}

// ---------------- weight convert + transpose/pack to f16 --------------------
// wsh (f16) element offsets:
//   Bp1 [cc32][q4][p16][nt4][kk4] @0     (packed Ws1; 32768)
//   Ws2T [64][64] @32768                 WtP [cc8][q][p][nt][kk] @36864 (8192)
//   Wa0T [16][64] @45056   Wa1T [16][64] @46080   Wc0T [64][16] @47104
//   We0T [4][32][64] @48128  We1T [4][32][32] @56320  We2T [4][32][32] @60416
// biases f32 (672 floats) in biasf.
__global__ void sm_convert_v7(
    const float* __restrict__ Ws1, const float* __restrict__ Ws2, const float* __restrict__ Wt,
    const float* __restrict__ Wa0, const float* __restrict__ Wa1, const float* __restrict__ Wc0,
    const float* __restrict__ We0, const float* __restrict__ We1, const float* __restrict__ We2,
    const float* __restrict__ bs1, const float* __restrict__ bs2, const float* __restrict__ bt,
    const float* __restrict__ ba0, const float* __restrict__ ba1, const float* __restrict__ bc0,
    const float* __restrict__ be0, const float* __restrict__ be1, const float* __restrict__ be2,
    short* __restrict__ wsh, float* __restrict__ biasf) {
  int d = blockIdx.x * 256 + threadIdx.x;
  if (d < 64512) {
    float v;
    if (d < 32768) {             // Bp1
      int kk = d & 3, nt = (d >> 2) & 3, p = (d >> 4) & 15, q = (d >> 8) & 3, cc = d >> 10;
      int k = cc * 16 + q * 4 + kk, o = nt * 16 + p;
      v = Ws1[k * 64 + o];
    }
    else if (d < 36864) { int r = d - 32768, o = r >> 6, k = r & 63;   v = Ws2[k * 64 + o]; }
    else if (d < 45056) {        // WtP
      int r = d - 36864;
      int kk = r & 3, nt = (r >> 2) & 3, p = (r >> 4) & 15, q = (r >> 8) & 3, cc = r >> 10;
      int k = cc * 16 + q * 4 + kk, o = nt * 16 + p;
      v = Wt[k * 64 + o];
    }
    else if (d < 46080) { int r = d - 45056, o = r >> 6, k = r & 63;   v = Wa0[k * 16 + o]; }
    else if (d < 47104) { int r = d - 46080, o = r >> 6, k = r & 63;   v = Wa1[k * 16 + o]; }
    else if (d < 48128) { int r = d - 47104, o = r >> 4, k = r & 15;   v = Wc0[k * 64 + o]; }
    else if (d < 56320) { int r = d - 48128, n = r >> 11, o = (r >> 6) & 31, i = r & 63; v = We0[n * 2048 + i * 32 + o]; }
    else if (d < 60416) { int r = d - 56320, n = r >> 10, o = (r >> 5) & 31, i = r & 31; v = We1[n * 1024 + i * 32 + o]; }
    else                { int r = d - 60416, n = r >> 10, o = (r >> 5) & 31, i = r & 31; v = We2[n * 1024 + i * 32 + o]; }
    wsh[d] = h_bits(v);
  } else if (d < 65184) {
    int r = d - 64512;
    float v;
    if      (r < 64)  v = bs1[r];
    else if (r < 128) v = bs2[r - 64];
    else if (r < 192) v = bt[r - 128];
    else if (r < 208) v = ba0[r - 192];
    else if (r < 224) v = ba1[r - 208];
    else if (r < 288) v = bc0[r - 224];
    else if (r < 416) v = be0[r - 288];
    else if (r < 544) v = be1[r - 416];
    else              v = be2[r - 544];
    biasf[r] = v;
  }
}

// ---------------- fused forward ---------------------------------------------
__global__ __launch_bounds__(256) void sm_fused_v7(
    const float* __restrict__ obs, const float* __restrict__ task,
    const short* __restrict__ wsh, const float* __restrict__ biasf,
    float* __restrict__ out) {
  const int tid  = threadIdx.x;
  const int wave = tid >> 6;
  const int lane = tid & 63;
  const int q    = lane >> 4;   // k-group (A/B) / row-reg group (C/D)
  const int p    = lane & 15;   // row (A) / col (B, C/D)
  const int lrow = wave * 16;
  const int wgrow  = blockIdx.x * 64;      // WG row base
  const int rowblk = wgrow + lrow;         // wave row base

  // LDS 28672B. Pre-barrier: x[64, stride 144] @0 | a[64, stride 48] @9216 |
  // ring[2][8192] @12288. Post-barrier: p[4][64, stride 80] overlays @0.
  __shared__ __align__(16) char lds[28672];
  char* x_lds = lds;
  char* a_lds = lds + 9216;
  char* ring  = lds + 12288;
  char* p_lds = lds;   // valid only after the big barrier

  const short* Bp1  = wsh;            // packed Ws1
  const short* Ws2T = wsh + 32768;
  const short* WtP  = wsh + 36864;    // packed Wt
  const short* Wa0T = wsh + 45056;
  const short* Wa1T = wsh + 46080;
  const short* Wc0T = wsh + 47104;
  const short* We0T = wsh + 48128;
  const short* We1T = wsh + 56320;
  const short* We2T = wsh + 60416;
  const float* bs1 = biasf;        const float* bs2 = biasf + 64;
  const float* bt  = biasf + 128;  const float* ba0 = biasf + 192;
  const float* ba1 = biasf + 208;  const float* bc0 = biasf + 224;
  const float* be0 = biasf + 288;  const float* be1 = biasf + 416;
  const float* be2 = biasf + 544;

  const f32x4 z4 = {0.f, 0.f, 0.f, 0.f};

  auto stx  = [&](int row, int col, float v) { *(short*)(x_lds + row * 144 + col * 2) = h_bits(v); };
  auto ldx4 = [&](int row, int k0) -> h16x4 { return *(const h16x4*)(x_lds + row * 144 + k0 * 2); };
  auto ldb  = [&](const short* W, int off) -> h16x4 { return *(const h16x4*)(W + off); };
  auto cvtA = [&](const u32x4& u) -> h16x4 {
    float4 v = __builtin_bit_cast(float4, u);
    h16x4 a;
    a[0] = (_Float16)v.x; a[1] = (_Float16)v.y;
    a[2] = (_Float16)v.z; a[3] = (_Float16)v.w;
    return a;
  };
  auto lo2 = [&](const u32x4& u) -> h16x4 { return __builtin_bit_cast(h16x4, (u32x2){u[0], u[1]}); };
  auto hi2 = [&](const u32x4& u) -> h16x4 { return __builtin_bit_cast(h16x4, (u32x2){u[2], u[3]}); };

  // Stage one 64rows x 32f32 chunk (8KB) of `base` at col k0 into ring buf.
  // Per wave: exactly 2 dma16 ops (j=0,1). Physical slot f = j*256+wave*64+lane
  // holds global (row=f>>3, col4 = (f&7) ^ (row&7)) — source-side swizzle.
  auto stage = [&](const float* base, int rowlen, int k0, int buf) {
#pragma unroll
    for (int j = 0; j < 2; ++j) {
      int f = j * 256 + wave * 64 + lane;
      int row = f >> 3;
      int cl = (f & 7) ^ (row & 7);
      const float* g = base + (size_t)(wgrow + row) * rowlen + k0 + cl * 4;
      dma16(g, ring + buf * 8192 + (j * 256 + wave * 64) * 16);
    }
  };
  // ds_read of own A-frag from staged chunk: row lrow+p, dword4 kb2*4+q (un-XOR)
  auto lda = [&](int buf, int kb2) -> u32x4 {
    return *(const u32x4*)(ring + buf * 8192 + (lrow + p) * 128 +
                           (((kb2 * 4 + q) ^ (p & 7)) * 16));
  };

  // ---- S1: X1 = relu(obs @ Ws1 + bs1), K=512 = 16 chunks of 32 ----
  f32x4 accX[4] = {z4, z4, z4, z4};
  {
    stage(obs, 512, 0, 0);
    for (int c = 0; c < 16; ++c) {
      if (c + 1 < 16) {
        stage(obs, 512, (c + 1) * 32, (c + 1) & 1);
        asm volatile("s_waitcnt vmcnt(2)" ::: "memory");  // dma(c) retired (2 newest are newer)
      } else {
        asm volatile("s_waitcnt vmcnt(0)" ::: "memory");
      }
      __syncthreads();                      // chunk c visible from all waves
#pragma unroll
      for (int kb2 = 0; kb2 < 2; ++kb2) {
        const int cc = c * 2 + kb2;
        const short* bp = Bp1 + ((cc * 4 + q) * 16 + p) * 16;
        u32x4 B0 = *(const u32x4*)bp;
        u32x4 B1 = *(const u32x4*)(bp + 8);
        h16x4 a = cvtA(lda(c & 1, kb2));
        accX[0] = MFMA16(a, lo2(B0), accX[0]);
        accX[1] = MFMA16(a, hi2(B0), accX[1]);
        accX[2] = MFMA16(a, lo2(B1), accX[2]);
        accX[3] = MFMA16(a, hi2(B1), accX[3]);
      }
      __syncthreads();                      // all done reading buf (c&1)
    }
  }
#pragma unroll
  for (int nt = 0; nt < 4; ++nt) {
    float bias = bs1[nt * 16 + p];
#pragma unroll
    for (int r = 0; r < 4; ++r)
      stx(lrow + 4 * q + r, nt * 16 + p, fmaxf(accX[nt][r] + bias, 0.f));
  }

  // Prefetch T chunk 0 now; it lands while S2 computes.
  stage(task, 128, 0, 0);

  // ---- S2: s = relu(X1 @ Ws2 + bs2), K=64 ----
  f32x4 accS[4] = {z4, z4, z4, z4};
#pragma unroll
  for (int kb = 0; kb < 4; ++kb) {
    h16x4 a = ldx4(lrow + p, kb * 16 + q * 4);
#pragma unroll
    for (int nt = 0; nt < 4; ++nt)
      accS[nt] = MFMA16(a, ldb(Ws2T, (nt * 16 + p) * 64 + kb * 16 + q * 4), accS[nt]);
  }
  float sf[4][4];
#pragma unroll
  for (int nt = 0; nt < 4; ++nt) {
    float bias = bs2[nt * 16 + p];
#pragma unroll
    for (int r = 0; r < 4; ++r) sf[nt][r] = fmaxf(accS[nt][r] + bias, 0.f);
  }
#pragma unroll
  for (int nt = 0; nt < 4; ++nt)
#pragma unroll
    for (int r = 0; r < 4; ++r) stx(lrow + 4 * q + r, nt * 16 + p, sf[nt][r]);

  // ---- T: t = relu(task @ Wt + bt), K=128 = 4 chunks of 32 ----
  f32x4 accT[4] = {z4, z4, z4, z4};
  {
    for (int c = 0; c < 4; ++c) {
      if (c + 1 < 4) {
        stage(task, 128, (c + 1) * 32, (c + 1) & 1);
        asm volatile("s_waitcnt vmcnt(2)" ::: "memory");
      } else {
        asm volatile("s_waitcnt vmcnt(0)" ::: "memory");
      }
      __syncthreads();
#pragma unroll
      for (int kb2 = 0; kb2 < 2; ++kb2) {
        const int cc = c * 2 + kb2;
        const short* bp = WtP + ((cc * 4 + q) * 16 + p) * 16;
        u32x4 B0 = *(const u32x4*)bp;
        u32x4 B1 = *(const u32x4*)(bp + 8);
        h16x4 a = cvtA(lda(c & 1, kb2));
        accT[0] = MFMA16(a, lo2(B0), accT[0]);
        accT[1] = MFMA16(a, hi2(B0), accT[1]);
        accT[2] = MFMA16(a, lo2(B1), accT[2]);
        accT[3] = MFMA16(a, hi2(B1), accT[3]);
      }
      __syncthreads();
    }
  }
  float r0f[4][4];
#pragma unroll
  for (int nt = 0; nt < 4; ++nt) {
    float bias = bt[nt * 16 + p];
#pragma unroll
    for (int r = 0; r < 4; ++r)
      r0f[nt][r] = sf[nt][r] * fmaxf(accT[nt][r] + bias, 0.f);
  }

  // ---- We0: m[j] = relu(s @ We0[j] + be0[j]), K=64, 32 cols each ----
  float mfr[4][2][4];
#pragma unroll
  for (int n = 0; n < 4; ++n) {
    f32x4 acc[2] = {z4, z4};
#pragma unroll
    for (int kb = 0; kb < 4; ++kb) {
      h16x4 a = ldx4(lrow + p, kb * 16 + q * 4);
#pragma unroll
      for (int nt = 0; nt < 2; ++nt)
        acc[nt] = MFMA16(a, ldb(We0T, (n * 32 + nt * 16 + p) * 64 + kb * 16 + q * 4), acc[nt]);
    }
#pragma unroll
    for (int nt = 0; nt < 2; ++nt) {
      float bias = be0[n * 32 + nt * 16 + p];
#pragma unroll
      for (int r = 0; r < 4; ++r) mfr[n][nt][r] = fmaxf(acc[nt][r] + bias, 0.f);
    }
  }

  // r0 -> x_lds
#pragma unroll
  for (int nt = 0; nt < 4; ++nt)
#pragma unroll
    for (int r = 0; r < 4; ++r) stx(lrow + 4 * q + r, nt * 16 + p, r0f[nt][r]);

  // ---- A0: softmax over groups of 4 of (r0 @ Wa0 + ba0) ----
  f32x4 accA = z4;
#pragma unroll
  for (int kb = 0; kb < 4; ++kb)
    accA = MFMA16(ldx4(lrow + p, kb * 16 + q * 4), ldb(Wa0T, p * 64 + kb * 16 + q * 4), accA);
  float a0v[4];
  {
    float bias = ba0[p];
#pragma unroll
    for (int r = 0; r < 4; ++r) {
      float v = accA[r] + bias;
      float mx = fmaxf(v, __shfl_xor(v, 1));
      mx = fmaxf(mx, __shfl_xor(mx, 2));
      float e = __expf(v - mx);
      float ssum = e + __shfl_xor(e, 1);
      ssum += __shfl_xor(ssum, 2);
      a0v[r] = e / ssum;
    }
  }
#pragma unroll
  for (int r = 0; r < 4; ++r)
    *(short*)(a_lds + (lrow + 4 * q + r) * 48 + p * 2) = h_bits(a0v[r]);

  // ---- combine: prev1[i][b][d] = sum_j a0[b][i][j] * m[j][b][d] ----
  float pv[4][2][4];
#pragma unroll
  for (int i = 0; i < 4; ++i)
#pragma unroll
    for (int nt = 0; nt < 2; ++nt)
#pragma unroll
      for (int r = 0; r < 4; ++r) pv[i][nt][r] = 0.f;
  const int sbase = lane & 48;
#pragma unroll
  for (int r = 0; r < 4; ++r) {
#pragma unroll
    for (int c = 0; c < 16; ++c) {
      float av = __shfl(a0v[r], sbase | c);
      pv[c >> 2][0][r] += av * mfr[c & 3][0][r];
      pv[c >> 2][1][r] += av * mfr[c & 3][1][r];
    }
  }

  // ---- Wc0: r = relu((a0 @ Wc0 + bc0) * r0), K=16 (one MFMA block) ----
  f32x4 accC[4] = {z4, z4, z4, z4};
  {
    h16x4 a = *(const h16x4*)(a_lds + (lrow + p) * 48 + q * 8);
#pragma unroll
    for (int nt = 0; nt < 4; ++nt)
      accC[nt] = MFMA16(a, ldb(Wc0T, (nt * 16 + p) * 16 + q * 4), accC[nt]);
  }
  float rf[4][4];
#pragma unroll
  for (int nt = 0; nt < 4; ++nt) {
    float bias = bc0[nt * 16 + p];
#pragma unroll
    for (int r = 0; r < 4; ++r)
      rf[nt][r] = fmaxf((accC[nt][r] + bias) * r0f[nt][r], 0.f);
  }
#pragma unroll
  for (int nt = 0; nt < 4; ++nt)
#pragma unroll
    for (int r = 0; r < 4; ++r) stx(lrow + 4 * q + r, nt * 16 + p, rf[nt][r]);

  // ---- A1: softmax(r @ Wa1 + ba1) ----
  f32x4 accA1 = z4;
#pragma unroll
  for (int kb = 0; kb < 4; ++kb)
    accA1 = MFMA16(ldx4(lrow + p, kb * 16 + q * 4), ldb(Wa1T, p * 64 + kb * 16 + q * 4), accA1);
  float a1v[4];
  {
    float bias = ba1[p];
#pragma unroll
    for (int r = 0; r < 4; ++r) {
      float v = accA1[r] + bias;
      float mx = fmaxf(v, __shfl_xor(v, 1));
      mx = fmaxf(mx, __shfl_xor(mx, 2));
      float e = __expf(v - mx);
      float ssum = e + __shfl_xor(e, 1);
      ssum += __shfl_xor(ssum, 2);
      a1v[r] = e / ssum;
    }
  }

  // ---- barrier: x/a/ring dead for ALL waves; p_lds overlays them ----
  __syncthreads();

  // ---- prev1 -> p_lds; E1: m1[n] = relu(prev1[n] @ We1[n] + be1[n]), K=32 ----
#pragma unroll
  for (int i = 0; i < 4; ++i)
#pragma unroll
    for (int nt = 0; nt < 2; ++nt)
#pragma unroll
      for (int r = 0; r < 4; ++r)
        *(short*)(p_lds + (i * 64 + lrow + 4 * q + r) * 80 + (nt * 16 + p) * 2) = h_bits(pv[i][nt][r]);

  float m1f[4][2][4];
#pragma unroll
  for (int n = 0; n < 4; ++n) {
    f32x4 acc[2] = {z4, z4};
#pragma unroll
    for (int kb = 0; kb < 2; ++kb) {
      h16x4 a = *(const h16x4*)(p_lds + (n * 64 + lrow + p) * 80 + kb * 32 + q * 8);
#pragma unroll
      for (int nt = 0; nt < 2; ++nt)
        acc[nt] = MFMA16(a, ldb(We1T, (n * 32 + nt * 16 + p) * 32 + kb * 16 + q * 4), acc[nt]);
    }
#pragma unroll
    for (int nt = 0; nt < 2; ++nt) {
      float bias = be1[n * 32 + nt * 16 + p];
#pragma unroll
      for (int r = 0; r < 4; ++r) m1f[n][nt][r] = fmaxf(acc[nt][r] + bias, 0.f);
    }
  }

  // ---- combine 2: prev2 = einsum(a1, m1) ----
#pragma unroll
  for (int i = 0; i < 4; ++i)
#pragma unroll
    for (int nt = 0; nt < 2; ++nt)
#pragma unroll
      for (int r = 0; r < 4; ++r) pv[i][nt][r] = 0.f;
#pragma unroll
  for (int r = 0; r < 4; ++r) {
#pragma unroll
    for (int c = 0; c < 16; ++c) {
      float av = __shfl(a1v[r], sbase | c);
      pv[c >> 2][0][r] += av * m1f[c & 3][0][r];
      pv[c >> 2][1][r] += av * m1f[c & 3][1][r];
    }
  }

  // ---- prev2 -> p_lds; E2 + relu + sum over n; store f32 ----
#pragma unroll
  for (int i = 0; i < 4; ++i)
#pragma unroll
    for (int nt = 0; nt < 2; ++nt)
#pragma unroll
      for (int r = 0; r < 4; ++r)
        *(short*)(p_lds + (i * 64 + lrow + 4 * q + r) * 80 + (nt * 16 + p) * 2) = h_bits(pv[i][nt][r]);

  float of[2][4] = {{0.f, 0.f, 0.f, 0.f}, {0.f, 0.f, 0.f, 0.f}};
#pragma unroll
  for (int n = 0; n < 4; ++n) {
    f32x4 acc[2] = {z4, z4};
#pragma unroll
    for (int kb = 0; kb < 2; ++kb) {
      h16x4 a = *(const h16x4*)(p_lds + (n * 64 + lrow + p) * 80 + kb * 32 + q * 8);
#pragma unroll
      for (int nt = 0; nt < 2; ++nt)
        acc[nt] = MFMA16(a, ldb(We2T, (n * 32 + nt * 16 + p) * 32 + kb * 16 + q * 4), acc[nt]);
    }
#pragma unroll
    for (int nt = 0; nt < 2; ++nt) {
      float bias = be2[n * 32 + nt * 16 + p];
#pragma unroll
      for (int r = 0; r < 4; ++r) of[nt][r] += fmaxf(acc[nt][r] + bias, 0.f);
    }
  }
#pragma unroll
  for (int nt = 0; nt < 2; ++nt)
#pragma unroll
    for (int r = 0; r < 4; ++r) {
      int grow = rowblk + 4 * q + r;
      out[(size_t)grow * 32 + nt * 16 + p] = of[nt][r];
    }
}

extern "C" void kernel_launch(void* const* d_in, const int* in_sizes, int n_in,
                              void* d_out, int out_size, void* d_ws, size_t ws_size,
                              hipStream_t stream) {
  (void)in_sizes; (void)n_in; (void)out_size; (void)ws_size;
  const float* obs  = (const float*)d_in[0];
  const float* task = (const float*)d_in[1];
  const float* Ws1 = (const float*)d_in[2];  const float* bs1 = (const float*)d_in[3];
  const float* Ws2 = (const float*)d_in[4];  const float* bs2 = (const float*)d_in[5];
  const float* Wt  = (const float*)d_in[6];  const float* bt  = (const float*)d_in[7];
  const float* Wa0 = (const float*)d_in[8];  const float* ba0 = (const float*)d_in[9];
  const float* Wa1 = (const float*)d_in[10]; const float* ba1 = (const float*)d_in[11];
  const float* Wc0 = (const float*)d_in[12]; const float* bc0 = (const float*)d_in[13];
  // d_in[14]=Wc1, d_in[15]=bc1: dead code in the reference (result unused)
  const float* We0 = (const float*)d_in[16]; const float* be0 = (const float*)d_in[17];
  const float* We1 = (const float*)d_in[18]; const float* be1 = (const float*)d_in[19];
  const float* We2 = (const float*)d_in[20]; const float* be2 = (const float*)d_in[21];

  short* wsh   = (short*)d_ws;
  float* biasf = (float*)((char*)d_ws + 129040);

  sm_convert_v7<<<dim3(255), dim3(256), 0, stream>>>(
      Ws1, Ws2, Wt, Wa0, Wa1, Wc0, We0, We1, We2,
      bs1, bs2, bt, ba0, ba1, bc0, be0, be1, be2,
      wsh, biasf);
  sm_fused_v7<<<dim3(1024), dim3(256), 0, stream>>>(
      obs, task, wsh, biasf, (float*)d_out);
}

// Round 9
// 71.325 us; speedup vs baseline: 1.3776x; 1.1170x over previous
//
#include <hip/hip_runtime.h>
#include <hip/hip_bf16.h>

// SoftModule fused forward, MI355X gfx950 — v9.
// v8 structure (vmem FIFO = staging DMAs only; raw s_barrier; double-buffered
// 12KB chunks) with the Bp1/WtP packing bijection FIXED (v8 dropped a bit:
// cc=d>>9 overlapped the pair field -> OOB reads -> garbage B).
// Layout now: elem d = c*2048 + kb2*1024 + pair*512 + q*128 + p*8 + ntip*4+kk
//   k = c*32+kb2*16+q*4+kk, o = pair*32+ntip*16+p; chunk = 4096B exactly,
//   stageB identity-copies it, ldbs reads kb2*2048+pair*1024+lane*16.
// Mid phases identical to v3..v7 (verified, absmax 0.03125).

using f32x4 = __attribute__((ext_vector_type(4))) float;
using h16x4 = __attribute__((ext_vector_type(4))) _Float16;
using u32x4 = __attribute__((ext_vector_type(4))) unsigned int;
using u32x2 = __attribute__((ext_vector_type(2))) unsigned int;

#define MFMA16(a, b, c) __builtin_amdgcn_mfma_f32_16x16x16f16((a), (b), (c), 0, 0, 0)

__device__ __forceinline__ short h_bits(float f) {
  _Float16 h = (_Float16)f;
  return __builtin_bit_cast(short, h);
}

// async global->LDS, 16B/lane; global addr per-lane, lds base wave-uniform
__device__ __forceinline__ void dma16(const void* g, char* l) {
  __builtin_amdgcn_global_load_lds(
      (const __attribute__((address_space(1))) unsigned int*)g,
      (__attribute__((address_space(3))) unsigned int*)l, 16, 0, 0);
}

// ---------------- weight convert + transpose/pack to f16 --------------------
// wsh (f16) element offsets:
//   Bp1 [c16][kb2_2][pair2][q4][p16][ntip2][kk4] @0   (packed Ws1; 32768)
//   Ws2T [64][64] @32768      WtP same packing, c4 @36864 (8192)
//   Wa0T [16][64] @45056   Wa1T [16][64] @46080   Wc0T [64][16] @47104
//   We0T [4][32][64] @48128  We1T [4][32][32] @56320  We2T [4][32][32] @60416
// biases f32 (672 floats) in biasf.
__global__ void sm_convert_v9(
    const float* __restrict__ Ws1, const float* __restrict__ Ws2, const float* __restrict__ Wt,
    const float* __restrict__ Wa0, const float* __restrict__ Wa1, const float* __restrict__ Wc0,
    const float* __restrict__ We0, const float* __restrict__ We1, const float* __restrict__ We2,
    const float* __restrict__ bs1, const float* __restrict__ bs2, const float* __restrict__ bt,
    const float* __restrict__ ba0, const float* __restrict__ ba1, const float* __restrict__ bc0,
    const float* __restrict__ be0, const float* __restrict__ be1, const float* __restrict__ be2,
    short* __restrict__ wsh, float* __restrict__ biasf) {
  int d = blockIdx.x * 256 + threadIdx.x;
  if (d < 64512) {
    float v;
    if (d < 32768) {             // Bp1 (fixed bijection)
      int kk   = d & 3;
      int ntip = (d >> 2) & 1;
      int p    = (d >> 3) & 15;
      int q    = (d >> 7) & 3;
      int pair = (d >> 9) & 1;
      int kb2  = (d >> 10) & 1;
      int c    = d >> 11;                       // 0..15
      int k = c * 32 + kb2 * 16 + q * 4 + kk;   // 0..511
      int o = pair * 32 + ntip * 16 + p;        // 0..63
      v = Ws1[k * 64 + o];
    }
    else if (d < 36864) { int r = d - 32768, o = r >> 6, k = r & 63;   v = Ws2[k * 64 + o]; }
    else if (d < 45056) {        // WtP, 8192, same packing (c = 0..3)
      int r = d - 36864;
      int kk   = r & 3;
      int ntip = (r >> 2) & 1;
      int p    = (r >> 3) & 15;
      int q    = (r >> 7) & 3;
      int pair = (r >> 9) & 1;
      int kb2  = (r >> 10) & 1;
      int c    = r >> 11;                       // 0..3
      int k = c * 32 + kb2 * 16 + q * 4 + kk;   // 0..127
      int o = pair * 32 + ntip * 16 + p;
      v = Wt[k * 64 + o];
    }
    else if (d < 46080) { int r = d - 45056, o = r >> 6, k = r & 63;   v = Wa0[k * 16 + o]; }
    else if (d < 47104) { int r = d - 46080, o = r >> 6, k = r & 63;   v = Wa1[k * 16 + o]; }
    else if (d < 48128) { int r = d - 47104, o = r >> 4, k = r & 15;   v = Wc0[k * 64 + o]; }
    else if (d < 56320) { int r = d - 48128, n = r >> 11, o = (r >> 6) & 31, i = r & 63; v = We0[n * 2048 + i * 32 + o]; }
    else if (d < 60416) { int r = d - 56320, n = r >> 10, o = (r >> 5) & 31, i = r & 31; v = We1[n * 1024 + i * 32 + o]; }
    else                { int r = d - 60416, n = r >> 10, o = (r >> 5) & 31, i = r & 31; v = We2[n * 1024 + i * 32 + o]; }
    wsh[d] = h_bits(v);
  } else if (d < 65184) {
    int r = d - 64512;
    float v;
    if      (r < 64)  v = bs1[r];
    else if (r < 128) v = bs2[r - 64];
    else if (r < 192) v = bt[r - 128];
    else if (r < 208) v = ba0[r - 192];
    else if (r < 224) v = ba1[r - 208];
    else if (r < 288) v = bc0[r - 224];
    else if (r < 416) v = be0[r - 288];
    else if (r < 544) v = be1[r - 416];
    else              v = be2[r - 544];
    biasf[r] = v;
  }
}

// ---------------- fused forward ---------------------------------------------
__global__ __launch_bounds__(256) void sm_fused_v9(
    const float* __restrict__ obs, const float* __restrict__ task,
    const short* __restrict__ wsh, const float* __restrict__ biasf,
    float* __restrict__ out) {
  const int tid  = threadIdx.x;
  const int wave = tid >> 6;
  const int lane = tid & 63;
  const int q    = lane >> 4;
  const int p    = lane & 15;
  const int lrow = wave * 16;
  const int wgrow  = blockIdx.x * 64;
  const int rowblk = wgrow + lrow;

  // LDS 36352B -> 4 WG/CU. Pre-barrier: x[64, stride 136] @0 |
  // a[64, stride 48] @8704 | ring[2][12288: A 8192 + B 4096] @11776.
  // Post-barrier: p[4][64, stride 80] overlays @0.
  __shared__ __align__(16) char lds[36352];
  char* x_lds = lds;
  char* a_lds = lds + 8704;
  char* ring  = lds + 11776;
  char* p_lds = lds;

  const short* Bp1  = wsh;
  const short* Ws2T = wsh + 32768;
  const short* WtP  = wsh + 36864;
  const short* Wa0T = wsh + 45056;
  const short* Wa1T = wsh + 46080;
  const short* Wc0T = wsh + 47104;
  const short* We0T = wsh + 48128;
  const short* We1T = wsh + 56320;
  const short* We2T = wsh + 60416;
  const float* bs1 = biasf;        const float* bs2 = biasf + 64;
  const float* bt  = biasf + 128;  const float* ba0 = biasf + 192;
  const float* ba1 = biasf + 208;  const float* bc0 = biasf + 224;
  const float* be0 = biasf + 288;  const float* be1 = biasf + 416;
  const float* be2 = biasf + 544;

  const f32x4 z4 = {0.f, 0.f, 0.f, 0.f};

  auto stx  = [&](int row, int col, float v) { *(short*)(x_lds + row * 136 + col * 2) = h_bits(v); };
  auto ldx4 = [&](int row, int k0) -> h16x4 { return *(const h16x4*)(x_lds + row * 136 + k0 * 2); };
  auto ldb  = [&](const short* W, int off) -> h16x4 { return *(const h16x4*)(W + off); };
  auto cvtA = [&](const u32x4& u) -> h16x4 {
    float4 v = __builtin_bit_cast(float4, u);
    h16x4 a;
    a[0] = (_Float16)v.x; a[1] = (_Float16)v.y;
    a[2] = (_Float16)v.z; a[3] = (_Float16)v.w;
    return a;
  };
  auto lo2 = [&](const u32x4& u) -> h16x4 { return __builtin_bit_cast(h16x4, (u32x2){u[0], u[1]}); };
  auto hi2 = [&](const u32x4& u) -> h16x4 { return __builtin_bit_cast(h16x4, (u32x2){u[2], u[3]}); };

  // Stage A: 64 rows x 32 f32 (8KB), source-side XOR swizzle (col4 ^= row&7),
  // linear LDS. Per wave: 2 dma. Stage B: linear 4KB identity copy.
  auto stageA = [&](const float* base, int rowlen, int k0, int buf) {
#pragma unroll
    for (int j = 0; j < 2; ++j) {
      int f = j * 256 + wave * 64 + lane;
      int row = f >> 3;
      int cl = (f & 7) ^ (row & 7);
      dma16(base + (size_t)(wgrow + row) * rowlen + k0 + cl * 4,
            ring + buf * 12288 + j * 4096 + wave * 1024);
    }
  };
  auto stageB = [&](const short* bsrc, int c, int buf) {
    dma16((const char*)bsrc + c * 4096 + (wave * 64 + lane) * 16,
          ring + buf * 12288 + 8192 + wave * 1024);
  };
  auto lda_ = [&](int buf, int kb2) -> u32x4 {
    return *(const u32x4*)(ring + buf * 12288 + (lrow + p) * 128 +
                           (((kb2 * 4 + q) ^ (p & 7)) * 16));
  };
  auto ldbs = [&](int buf, int kb2, int pair) -> u32x4 {
    return *(const u32x4*)(ring + buf * 12288 + 8192 + kb2 * 2048 + pair * 1024 + lane * 16);
  };

  // ---- S1: X1 = relu(obs @ Ws1 + bs1), K=512 = 16 chunks of 32 ----
  f32x4 accX[4] = {z4, z4, z4, z4};
  {
    stageA(obs, 512, 0, 0); stageB(Bp1, 0, 0);
    for (int c = 0; c < 16; ++c) {
      asm volatile("s_waitcnt vmcnt(0)" ::: "memory");   // own chunk-c DMAs landed
      __builtin_amdgcn_s_barrier();                      // raw: no drain; all waves' landed
      __builtin_amdgcn_sched_barrier(0);
      if (c + 1 < 16) {                                  // prefetch c+1, stays in flight
        stageA(obs, 512, (c + 1) * 32, (c + 1) & 1);
        stageB(Bp1, c + 1, (c + 1) & 1);
      }
      __builtin_amdgcn_sched_barrier(0);
      const int buf = c & 1;
#pragma unroll
      for (int kb2 = 0; kb2 < 2; ++kb2) {
        h16x4 a = cvtA(lda_(buf, kb2));
        u32x4 B0 = ldbs(buf, kb2, 0);
        u32x4 B1 = ldbs(buf, kb2, 1);
        accX[0] = MFMA16(a, lo2(B0), accX[0]);
        accX[1] = MFMA16(a, hi2(B0), accX[1]);
        accX[2] = MFMA16(a, lo2(B1), accX[2]);
        accX[3] = MFMA16(a, hi2(B1), accX[3]);
      }
    }
  }

  // Prefetch T chunk 0 (lands during epilogue+S2). buf0 last read at c=14: safe.
  stageA(task, 128, 0, 0); stageB(WtP, 0, 0);

#pragma unroll
  for (int nt = 0; nt < 4; ++nt) {
    float bias = bs1[nt * 16 + p];
#pragma unroll
    for (int r = 0; r < 4; ++r)
      stx(lrow + 4 * q + r, nt * 16 + p, fmaxf(accX[nt][r] + bias, 0.f));
  }

  // ---- S2: s = relu(X1 @ Ws2 + bs2), K=64 ----
  f32x4 accS[4] = {z4, z4, z4, z4};
#pragma unroll
  for (int kb = 0; kb < 4; ++kb) {
    h16x4 a = ldx4(lrow + p, kb * 16 + q * 4);
#pragma unroll
    for (int nt = 0; nt < 4; ++nt)
      accS[nt] = MFMA16(a, ldb(Ws2T, (nt * 16 + p) * 64 + kb * 16 + q * 4), accS[nt]);
  }
  float sf[4][4];
#pragma unroll
  for (int nt = 0; nt < 4; ++nt) {
    float bias = bs2[nt * 16 + p];
#pragma unroll
    for (int r = 0; r < 4; ++r) sf[nt][r] = fmaxf(accS[nt][r] + bias, 0.f);
  }
#pragma unroll
  for (int nt = 0; nt < 4; ++nt)
#pragma unroll
    for (int r = 0; r < 4; ++r) stx(lrow + 4 * q + r, nt * 16 + p, sf[nt][r]);

  // ---- T: t = relu(task @ Wt + bt), K=128 = 4 chunks ----
  f32x4 accT[4] = {z4, z4, z4, z4};
  {
    for (int c = 0; c < 4; ++c) {
      asm volatile("s_waitcnt vmcnt(0)" ::: "memory");
      __builtin_amdgcn_s_barrier();
      __builtin_amdgcn_sched_barrier(0);
      if (c + 1 < 4) {
        stageA(task, 128, (c + 1) * 32, (c + 1) & 1);
        stageB(WtP, c + 1, (c + 1) & 1);
      }
      __builtin_amdgcn_sched_barrier(0);
      const int buf = c & 1;
#pragma unroll
      for (int kb2 = 0; kb2 < 2; ++kb2) {
        h16x4 a = cvtA(lda_(buf, kb2));
        u32x4 B0 = ldbs(buf, kb2, 0);
        u32x4 B1 = ldbs(buf, kb2, 1);
        accT[0] = MFMA16(a, lo2(B0), accT[0]);
        accT[1] = MFMA16(a, hi2(B0), accT[1]);
        accT[2] = MFMA16(a, lo2(B1), accT[2]);
        accT[3] = MFMA16(a, hi2(B1), accT[3]);
      }
    }
  }
  float r0f[4][4];
#pragma unroll
  for (int nt = 0; nt < 4; ++nt) {
    float bias = bt[nt * 16 + p];
#pragma unroll
    for (int r = 0; r < 4; ++r)
      r0f[nt][r] = sf[nt][r] * fmaxf(accT[nt][r] + bias, 0.f);
  }

  // ---- We0: m[j] = relu(s @ We0[j] + be0[j]), K=64, 32 cols each ----
  float mfr[4][2][4];
#pragma unroll
  for (int n = 0; n < 4; ++n) {
    f32x4 acc[2] = {z4, z4};
#pragma unroll
    for (int kb = 0; kb < 4; ++kb) {
      h16x4 a = ldx4(lrow + p, kb * 16 + q * 4);
#pragma unroll
      for (int nt = 0; nt < 2; ++nt)
        acc[nt] = MFMA16(a, ldb(We0T, (n * 32 + nt * 16 + p) * 64 + kb * 16 + q * 4), acc[nt]);
    }
#pragma unroll
    for (int nt = 0; nt < 2; ++nt) {
      float bias = be0[n * 32 + nt * 16 + p];
#pragma unroll
      for (int r = 0; r < 4; ++r) mfr[n][nt][r] = fmaxf(acc[nt][r] + bias, 0.f);
    }
  }

  // r0 -> x_lds
#pragma unroll
  for (int nt = 0; nt < 4; ++nt)
#pragma unroll
    for (int r = 0; r < 4; ++r) stx(lrow + 4 * q + r, nt * 16 + p, r0f[nt][r]);

  // ---- A0: softmax over groups of 4 of (r0 @ Wa0 + ba0) ----
  f32x4 accA = z4;
#pragma unroll
  for (int kb = 0; kb < 4; ++kb)
    accA = MFMA16(ldx4(lrow + p, kb * 16 + q * 4), ldb(Wa0T, p * 64 + kb * 16 + q * 4), accA);
  float a0v[4];
  {
    float bias = ba0[p];
#pragma unroll
    for (int r = 0; r < 4; ++r) {
      float v = accA[r] + bias;
      float mx = fmaxf(v, __shfl_xor(v, 1));
      mx = fmaxf(mx, __shfl_xor(mx, 2));
      float e = __expf(v - mx);
      float ssum = e + __shfl_xor(e, 1);
      ssum += __shfl_xor(ssum, 2);
      a0v[r] = e / ssum;
    }
  }
#pragma unroll
  for (int r = 0; r < 4; ++r)
    *(short*)(a_lds + (lrow + 4 * q + r) * 48 + p * 2) = h_bits(a0v[r]);

  // ---- combine: prev1[i][b][d] = sum_j a0[b][i][j] * m[j][b][d] ----
  float pv[4][2][4];
#pragma unroll
  for (int i = 0; i < 4; ++i)
#pragma unroll
    for (int nt = 0; nt < 2; ++nt)
#pragma unroll
      for (int r = 0; r < 4; ++r) pv[i][nt][r] = 0.f;
  const int sbase = lane & 48;
#pragma unroll
  for (int r = 0; r < 4; ++r) {
#pragma unroll
    for (int c = 0; c < 16; ++c) {
      float av = __shfl(a0v[r], sbase | c);
      pv[c >> 2][0][r] += av * mfr[c & 3][0][r];
      pv[c >> 2][1][r] += av * mfr[c & 3][1][r];
    }
  }

  // ---- Wc0: r = relu((a0 @ Wc0 + bc0) * r0), K=16 ----
  f32x4 accC[4] = {z4, z4, z4, z4};
  {
    h16x4 a = *(const h16x4*)(a_lds + (lrow + p) * 48 + q * 8);
#pragma unroll
    for (int nt = 0; nt < 4; ++nt)
      accC[nt] = MFMA16(a, ldb(Wc0T, (nt * 16 + p) * 16 + q * 4), accC[nt]);
  }
  float rf[4][4];
#pragma unroll
  for (int nt = 0; nt < 4; ++nt) {
    float bias = bc0[nt * 16 + p];
#pragma unroll
    for (int r = 0; r < 4; ++r)
      rf[nt][r] = fmaxf((accC[nt][r] + bias) * r0f[nt][r], 0.f);
  }
#pragma unroll
  for (int nt = 0; nt < 4; ++nt)
#pragma unroll
    for (int r = 0; r < 4; ++r) stx(lrow + 4 * q + r, nt * 16 + p, rf[nt][r]);

  // ---- A1: softmax(r @ Wa1 + ba1) ----
  f32x4 accA1 = z4;
#pragma unroll
  for (int kb = 0; kb < 4; ++kb)
    accA1 = MFMA16(ldx4(lrow + p, kb * 16 + q * 4), ldb(Wa1T, p * 64 + kb * 16 + q * 4), accA1);
  float a1v[4];
  {
    float bias = ba1[p];
#pragma unroll
    for (int r = 0; r < 4; ++r) {
      float v = accA1[r] + bias;
      float mx = fmaxf(v, __shfl_xor(v, 1));
      mx = fmaxf(mx, __shfl_xor(mx, 2));
      float e = __expf(v - mx);
      float ssum = e + __shfl_xor(e, 1);
      ssum += __shfl_xor(ssum, 2);
      a1v[r] = e / ssum;
    }
  }

  // ---- barrier: x/a/ring dead for ALL waves; p_lds overlays them ----
  __syncthreads();

  // ---- prev1 -> p_lds; E1: m1[n] = relu(prev1[n] @ We1[n] + be1[n]), K=32 ----
#pragma unroll
  for (int i = 0; i < 4; ++i)
#pragma unroll
    for (int nt = 0; nt < 2; ++nt)
#pragma unroll
      for (int r = 0; r < 4; ++r)
        *(short*)(p_lds + (i * 64 + lrow + 4 * q + r) * 80 + (nt * 16 + p) * 2) = h_bits(pv[i][nt][r]);

  float m1f[4][2][4];
#pragma unroll
  for (int n = 0; n < 4; ++n) {
    f32x4 acc[2] = {z4, z4};
#pragma unroll
    for (int kb = 0; kb < 2; ++kb) {
      h16x4 a = *(const h16x4*)(p_lds + (n * 64 + lrow + p) * 80 + kb * 32 + q * 8);
#pragma unroll
      for (int nt = 0; nt < 2; ++nt)
        acc[nt] = MFMA16(a, ldb(We1T, (n * 32 + nt * 16 + p) * 32 + kb * 16 + q * 4), acc[nt]);
    }
#pragma unroll
    for (int nt = 0; nt < 2; ++nt) {
      float bias = be1[n * 32 + nt * 16 + p];
#pragma unroll
      for (int r = 0; r < 4; ++r) m1f[n][nt][r] = fmaxf(acc[nt][r] + bias, 0.f);
    }
  }

  // ---- combine 2: prev2 = einsum(a1, m1) ----
#pragma unroll
  for (int i = 0; i < 4; ++i)
#pragma unroll
    for (int nt = 0; nt < 2; ++nt)
#pragma unroll
      for (int r = 0; r < 4; ++r) pv[i][nt][r] = 0.f;
#pragma unroll
  for (int r = 0; r < 4; ++r) {
#pragma unroll
    for (int c = 0; c < 16; ++c) {
      float av = __shfl(a1v[r], sbase | c);
      pv[c >> 2][0][r] += av * m1f[c & 3][0][r];
      pv[c >> 2][1][r] += av * m1f[c & 3][1][r];
    }
  }

  // ---- prev2 -> p_lds; E2 + relu + sum over n; store f32 ----
#pragma unroll
  for (int i = 0; i < 4; ++i)
#pragma unroll
    for (int nt = 0; nt < 2; ++nt)
#pragma unroll
      for (int r = 0; r < 4; ++r)
        *(short*)(p_lds + (i * 64 + lrow + 4 * q + r) * 80 + (nt * 16 + p) * 2) = h_bits(pv[i][nt][r]);

  float of[2][4] = {{0.f, 0.f, 0.f, 0.f}, {0.f, 0.f, 0.f, 0.f}};
#pragma unroll
  for (int n = 0; n < 4; ++n) {
    f32x4 acc[2] = {z4, z4};
#pragma unroll
    for (int kb = 0; kb < 2; ++kb) {
      h16x4 a = *(const h16x4*)(p_lds + (n * 64 + lrow + p) * 80 + kb * 32 + q * 8);
#pragma unroll
      for (int nt = 0; nt < 2; ++nt)
        acc[nt] = MFMA16(a, ldb(We2T, (n * 32 + nt * 16 + p) * 32 + kb * 16 + q * 4), acc[nt]);
    }
#pragma unroll
    for (int nt = 0; nt < 2; ++nt) {
      float bias = be2[n * 32 + nt * 16 + p];
#pragma unroll
      for (int r = 0; r < 4; ++r) of[nt][r] += fmaxf(acc[nt][r] + bias, 0.f);
    }
  }
#pragma unroll
  for (int nt = 0; nt < 2; ++nt)
#pragma unroll
    for (int r = 0; r < 4; ++r) {
      int grow = rowblk + 4 * q + r;
      out[(size_t)grow * 32 + nt * 16 + p] = of[nt][r];
    }
}

extern "C" void kernel_launch(void* const* d_in, const int* in_sizes, int n_in,
                              void* d_out, int out_size, void* d_ws, size_t ws_size,
                              hipStream_t stream) {
  (void)in_sizes; (void)n_in; (void)out_size; (void)ws_size;
  const float* obs  = (const float*)d_in[0];
  const float* task = (const float*)d_in[1];
  const float* Ws1 = (const float*)d_in[2];  const float* bs1 = (const float*)d_in[3];
  const float* Ws2 = (const float*)d_in[4];  const float* bs2 = (const float*)d_in[5];
  const float* Wt  = (const float*)d_in[6];  const float* bt  = (const float*)d_in[7];
  const float* Wa0 = (const float*)d_in[8];  const float* ba0 = (const float*)d_in[9];
  const float* Wa1 = (const float*)d_in[10]; const float* ba1 = (const float*)d_in[11];
  const float* Wc0 = (const float*)d_in[12]; const float* bc0 = (const float*)d_in[13];
  // d_in[14]=Wc1, d_in[15]=bc1: dead code in the reference (result unused)
  const float* We0 = (const float*)d_in[16]; const float* be0 = (const float*)d_in[17];
  const float* We1 = (const float*)d_in[18]; const float* be1 = (const float*)d_in[19];
  const float* We2 = (const float*)d_in[20]; const float* be2 = (const float*)d_in[21];

  short* wsh   = (short*)d_ws;
  float* biasf = (float*)((char*)d_ws + 129040);

  sm_convert_v9<<<dim3(255), dim3(256), 0, stream>>>(
      Ws1, Ws2, Wt, Wa0, Wa1, Wc0, We0, We1, We2,
      bs1, bs2, bt, ba0, ba1, bc0, be0, be1, be2,
      wsh, biasf);
  sm_fused_v9<<<dim3(1024), dim3(256), 0, stream>>>(
      obs, task, wsh, biasf, (float*)d_out);
}